// Round 3
// baseline (7679.909 us; speedup 1.0000x reference)
//
#include <hip/hip_runtime.h>

#define NHEADS 40
#define HDIM 128
#define SEQ 1024
#define HID 5120
#define KDIM 5120
#define NEG_BIG (-1e30f)

// fp32 GEMM: C[M,N] = A[M,K] * B[N,K]^T (both K-contiguous). 128x128 tile,
// BK=32, 256 threads, 8x8 micro-tile per thread.
// EPI=0: scatter C into Q/K/V [B,NH,S,D] (N=15360). EPI=1: row-major C[M,5120].
template <int EPI>
__launch_bounds__(256)
__global__ void gemm_bt(const float* __restrict__ A, const float* __restrict__ B,
                        float* __restrict__ O0, float* __restrict__ O1,
                        float* __restrict__ O2) {
    __shared__ float lA[32][132];  // [k][m], +4 pad (stride 132: 16B-aligned rows)
    __shared__ float lB[32][132];  // [k][n]
    const int t = threadIdx.x;
    const int tm = t >> 4, tn = t & 15;
    const int m0 = blockIdx.y * 128, n0 = blockIdx.x * 128;
    const int sr = t >> 3;        // staging row 0..31
    const int sk = (t & 7) * 4;   // staging k 0..28

    float acc[8][8] = {};
    const float* Ag = A + (long)(m0 + sr) * KDIM + sk;
    const float* Bg = B + (long)(n0 + sr) * KDIM + sk;

    for (int k0 = 0; k0 < KDIM; k0 += 32) {
        __syncthreads();
#pragma unroll
        for (int p = 0; p < 4; ++p) {
            const float4 av = *(const float4*)(Ag + (long)p * 32 * KDIM + k0);
            const float4 bv = *(const float4*)(Bg + (long)p * 32 * KDIM + k0);
            const int m = sr + p * 32;
            lA[sk + 0][m] = av.x; lA[sk + 1][m] = av.y;
            lA[sk + 2][m] = av.z; lA[sk + 3][m] = av.w;
            lB[sk + 0][m] = bv.x; lB[sk + 1][m] = bv.y;
            lB[sk + 2][m] = bv.z; lB[sk + 3][m] = bv.w;
        }
        __syncthreads();
#pragma unroll 4
        for (int kk = 0; kk < 32; ++kk) {
            const float4 a0 = *(const float4*)&lA[kk][tm * 4];
            const float4 a1 = *(const float4*)&lA[kk][64 + tm * 4];
            const float4 b0 = *(const float4*)&lB[kk][tn * 4];
            const float4 b1 = *(const float4*)&lB[kk][64 + tn * 4];
            const float ar[8] = {a0.x, a0.y, a0.z, a0.w, a1.x, a1.y, a1.z, a1.w};
            const float br[8] = {b0.x, b0.y, b0.z, b0.w, b1.x, b1.y, b1.z, b1.w};
#pragma unroll
            for (int r = 0; r < 8; ++r)
#pragma unroll
                for (int c = 0; c < 8; ++c) acc[r][c] += ar[r] * br[c];
        }
    }

    const int sec = n0 / HID;              // 0=q 1=k 2=v (EPI=0; n-tile never straddles)
    const int h = (n0 % HID) / HDIM;       // head (128 | 5120)
#pragma unroll
    for (int r8 = 0; r8 < 8; ++r8) {
        const int mi = m0 + ((r8 < 4) ? (tm * 4 + r8) : (64 + tm * 4 + (r8 - 4)));
        float4 v0, v1;
        v0.x = acc[r8][0]; v0.y = acc[r8][1]; v0.z = acc[r8][2]; v0.w = acc[r8][3];
        v1.x = acc[r8][4]; v1.y = acc[r8][5]; v1.z = acc[r8][6]; v1.w = acc[r8][7];
        if (EPI == 0) {
            const int b = mi >> 10, s = mi & 1023;
            float* Ob = (sec == 0) ? O0 : (sec == 1) ? O1 : O2;
            float* dst = Ob + ((long)(b * NHEADS + h) * SEQ + s) * HDIM;
            *(float4*)(dst + tn * 4) = v0;
            *(float4*)(dst + 64 + tn * 4) = v1;
        } else {
            float* dst = O0 + (long)mi * HID + n0;
            *(float4*)(dst + tn * 4) = v0;
            *(float4*)(dst + 64 + tn * 4) = v1;
        }
    }
}

// fp32 flash attention w/ ALiBi + causal. grid (S/32, NH, B), 256 threads.
// 32 q-rows per block, kv-tile 32, 2x2 S micro-tile, 2x8 O micro-tile.
__launch_bounds__(256)
__global__ void attn_fwd(const float* __restrict__ Q, const float* __restrict__ K,
                         const float* __restrict__ V, const float* __restrict__ mask,
                         float* __restrict__ ATT) {
    __shared__ float lQ[128][36];  // [d][q]  (transposed; 61KB total static LDS)
    __shared__ float lK[128][36];  // [d][kv]
    __shared__ float lV[32][132];  // [kv][d] natural
    __shared__ float lP[32][36];   // [kv][q]
    __shared__ float lM[SEQ];      // clamped mask row

    const int t = threadIdx.x;
    const int tm = t >> 4, tn = t & 15;
    const int qt = blockIdx.x, h = blockIdx.y, b = blockIdx.z;
    const int q0 = qt * 32;
    const long bh = (long)b * NHEADS + h;
    const float* Qh = Q + bh * SEQ * HDIM;
    const float* Kh = K + bh * SEQ * HDIM;
    const float* Vh = V + bh * SEQ * HDIM;

    {   // mask[h][S-1][j] finite for all j; clamp so no inf/NaN enters softmax
        const float* mrow = mask + ((long)h * SEQ + (SEQ - 1)) * SEQ;
#pragma unroll
        for (int p = 0; p < 4; ++p) {
            const int j = t + p * 256;
            lM[j] = fminf(fmaxf(mrow[j], NEG_BIG), 1e30f);
        }
    }
    {   // stage Q 32x128 transposed -> lQ[d][q]
        const int row = t >> 5;          // 0..7 (+8p)
        const int col = (t & 31) * 4;    // d 0..124
#pragma unroll
        for (int p = 0; p < 4; ++p) {
            const float4 qv = *(const float4*)(Qh + (long)(q0 + row + p * 8) * HDIM + col);
            lQ[col + 0][row + p * 8] = qv.x; lQ[col + 1][row + p * 8] = qv.y;
            lQ[col + 2][row + p * 8] = qv.z; lQ[col + 3][row + p * 8] = qv.w;
        }
    }

    float O[2][8] = {};
    float mrun[2] = {NEG_BIG, NEG_BIG};
    float lrun[2] = {0.f, 0.f};
    const int i0 = q0 + tm * 2;               // this thread's q rows: i0, i0+1
    const float scale = 0.08838834764831845f; // 1/sqrt(128)

    __syncthreads();

    for (int kt = 0; kt <= qt; ++kt) {
        const int kv0 = kt * 32;
        if (kt) __syncthreads();  // protect lK/lV/lP from previous iteration
        {   // stage K (transposed) + V (natural)
            const int row = t >> 5;
            const int col = (t & 31) * 4;
#pragma unroll
            for (int p = 0; p < 4; ++p) {
                const float4 kv = *(const float4*)(Kh + (long)(kv0 + row + p * 8) * HDIM + col);
                lK[col + 0][row + p * 8] = kv.x; lK[col + 1][row + p * 8] = kv.y;
                lK[col + 2][row + p * 8] = kv.z; lK[col + 3][row + p * 8] = kv.w;
                const float4 vv = *(const float4*)(Vh + (long)(kv0 + row + p * 8) * HDIM + col);
                *(float4*)&lV[row + p * 8][col] = vv;
            }
        }
        __syncthreads();

        // S[2][2] = Q K^T over d=128
        float S00 = 0.f, S01 = 0.f, S10 = 0.f, S11 = 0.f;
#pragma unroll 8
        for (int d = 0; d < 128; ++d) {
            const float2 qa = *(const float2*)&lQ[d][tm * 2];
            const float2 ka = *(const float2*)&lK[d][tn * 2];
            S00 += qa.x * ka.x; S01 += qa.x * ka.y;
            S10 += qa.y * ka.x; S11 += qa.y * ka.y;
        }
        float Sv[2][2] = {{S00, S01}, {S10, S11}};

        // scale + alibi + causal (finite sentinel), row-max over the tile
        float tmax[2] = {NEG_BIG, NEG_BIG};
#pragma unroll
        for (int r = 0; r < 2; ++r)
#pragma unroll
            for (int c = 0; c < 2; ++c) {
                const int j = kv0 + tn * 2 + c;
                float v = Sv[r][c] * scale + lM[j];
                if (j > i0 + r) v = NEG_BIG;
                Sv[r][c] = v;
                tmax[r] = fmaxf(tmax[r], v);
            }
#pragma unroll
        for (int x = 1; x < 16; x <<= 1) {
            tmax[0] = fmaxf(tmax[0], __shfl_xor(tmax[0], x, 64));
            tmax[1] = fmaxf(tmax[1], __shfl_xor(tmax[1], x, 64));
        }
        float alpha[2], rsum[2] = {0.f, 0.f};
#pragma unroll
        for (int r = 0; r < 2; ++r) {
            const float mnew = fmaxf(mrun[r], tmax[r]);
            alpha[r] = __expf(mrun[r] - mnew);  // finite - finite
            mrun[r] = mnew;
        }
#pragma unroll
        for (int r = 0; r < 2; ++r)
#pragma unroll
            for (int c = 0; c < 2; ++c) {
                const float pv = __expf(Sv[r][c] - mrun[r]);
                rsum[r] += pv;
                lP[tn * 2 + c][tm * 2 + r] = pv;  // lP[kv][q]
            }
#pragma unroll
        for (int x = 1; x < 16; x <<= 1) {
            rsum[0] += __shfl_xor(rsum[0], x, 64);
            rsum[1] += __shfl_xor(rsum[1], x, 64);
        }
#pragma unroll
        for (int r = 0; r < 2; ++r) lrun[r] = lrun[r] * alpha[r] + rsum[r];
#pragma unroll
        for (int dt = 0; dt < 8; ++dt) { O[0][dt] *= alpha[0]; O[1][dt] *= alpha[1]; }
        __syncthreads();  // lP visible to all

        // O[2][8] += P[q][kv] * V[kv][d], this thread's d-cols: tn*8 .. tn*8+7
#pragma unroll 4
        for (int kv = 0; kv < 32; ++kv) {
            const float2 pf = *(const float2*)&lP[kv][tm * 2];
            const float4 va = *(const float4*)&lV[kv][tn * 8];
            const float4 vb = *(const float4*)&lV[kv][tn * 8 + 4];
            O[0][0] += pf.x * va.x; O[0][1] += pf.x * va.y;
            O[0][2] += pf.x * va.z; O[0][3] += pf.x * va.w;
            O[0][4] += pf.x * vb.x; O[0][5] += pf.x * vb.y;
            O[0][6] += pf.x * vb.z; O[0][7] += pf.x * vb.w;
            O[1][0] += pf.y * va.x; O[1][1] += pf.y * va.y;
            O[1][2] += pf.y * va.z; O[1][3] += pf.y * va.w;
            O[1][4] += pf.y * vb.x; O[1][5] += pf.y * vb.y;
            O[1][6] += pf.y * vb.z; O[1][7] += pf.y * vb.w;
        }
    }

    // epilogue: ATT[b][s][h*128 + d], rows i0/i0+1, cols tn*8..tn*8+7
    const float inv0 = 1.f / lrun[0], inv1 = 1.f / lrun[1];
    float* dst0 = ATT + (long)(b * SEQ + i0 + 0) * HID + h * HDIM + tn * 8;
    float* dst1 = ATT + (long)(b * SEQ + i0 + 1) * HID + h * HDIM + tn * 8;
    float4 o;
    o.x = O[0][0] * inv0; o.y = O[0][1] * inv0; o.z = O[0][2] * inv0; o.w = O[0][3] * inv0;
    *(float4*)dst0 = o;
    o.x = O[0][4] * inv0; o.y = O[0][5] * inv0; o.z = O[0][6] * inv0; o.w = O[0][7] * inv0;
    *(float4*)(dst0 + 4) = o;
    o.x = O[1][0] * inv1; o.y = O[1][1] * inv1; o.z = O[1][2] * inv1; o.w = O[1][3] * inv1;
    *(float4*)dst1 = o;
    o.x = O[1][4] * inv1; o.y = O[1][5] * inv1; o.z = O[1][6] * inv1; o.w = O[1][7] * inv1;
    *(float4*)(dst1 + 4) = o;
}

extern "C" void kernel_launch(void* const* d_in, const int* in_sizes, int n_in,
                              void* d_out, int out_size, void* d_ws, size_t ws_size,
                              hipStream_t stream) {
    const float* hid  = (const float*)d_in[0];  // [2,1024,5120]
    const float* mask = (const float*)d_in[1];  // [40,1024,1024]
    const float* wpk  = (const float*)d_in[2];  // [15360,5120]
    const float* opr  = (const float*)d_in[3];  // [5120,5120]
    float* out = (float*)d_out;                 // [2,1024,5120]

    const size_t SZF = (size_t)2 * NHEADS * SEQ * HDIM;  // 10,485,760 floats
    float* Qb = (float*)d_ws;
    float* Kb = Qb + SZF;
    float* Vb = Kb + SZF;
    float* At = Vb + SZF;   // ws use: 4 x 41.9 MB = 167.8 MB

    // QKV projection: [2048,15360] = hid * W_pack^T -> Q/K/V [B,NH,S,D]
    gemm_bt<0><<<dim3(120, 16), 256, 0, stream>>>(hid, wpk, Qb, Kb, Vb);
    // flash attention (fp32, ALiBi + causal) -> At [B*S, HID]
    attn_fwd<<<dim3(32, NHEADS, 2), 256, 0, stream>>>(Qb, Kb, Vb, mask, At);
    // output projection: [2048,5120] = At * o_proj^T -> d_out
    gemm_bt<1><<<dim3(40, 16), 256, 0, stream>>>(At, opr, out, nullptr, nullptr);
}